// Round 6
// baseline (765.641 us; speedup 1.0000x reference)
//
#include <hip/hip_runtime.h>
#include <hip/hip_bf16.h>
#include <stdint.h>

#define DIM   512
#define BATCH 64
#define KENC  1024          // encoded row: [hi(512) | lo(512)]
#define BM    256
#define BN    256
#define BKT   32
#define NKT   16
#define BUFE  32768         // ushorts per LDS buffer (64 KB): 4 planes * 8192

typedef __attribute__((ext_vector_type(8))) short short8;
typedef __attribute__((ext_vector_type(4))) float floatx4;

__device__ __forceinline__ ushort f2bf(float f) {
    __hip_bfloat16 h = __float2bfloat16(f);
    return *(ushort*)&h;
}
__device__ __forceinline__ float bf2f(ushort u) {
    __hip_bfloat16 h = *(__hip_bfloat16*)&u;
    return (float)h;
}

typedef __attribute__((address_space(3))) uint32_t lds_u32;
typedef const __attribute__((address_space(1))) uint32_t glb_u32;
__device__ __forceinline__ void gload16(const ushort* g, ushort* l) {
    __builtin_amdgcn_global_load_lds((glb_u32*)g, (lds_u32*)l, 16, 0, 0);
}

#define WAITVM(N) asm volatile("s_waitcnt vmcnt(" #N ")" ::: "memory")
#define BARRIER() do { __builtin_amdgcn_s_barrier(); __builtin_amdgcn_sched_barrier(0); } while (0)

__global__ __launch_bounds__(256) void norm_partial_kernel(const float* __restrict__ x,
                                                           float* __restrict__ partial) {
    int b = blockIdx.y;
    int i = blockIdx.x;
    const float4* xv = (const float4*)(x + (size_t)b * DIM * DIM + (size_t)i * (DIM * DIM / 16));
    float s = 0.f;
    #pragma unroll
    for (int r = 0; r < 16; ++r) {
        float4 v = xv[r * 256 + threadIdx.x];
        s += v.x * v.x + v.y * v.y + v.z * v.z + v.w * v.w;
    }
    #pragma unroll
    for (int off = 32; off > 0; off >>= 1) s += __shfl_down(s, off, 64);
    __shared__ float red[4];
    int lane = threadIdx.x & 63, wid = threadIdx.x >> 6;
    if (lane == 0) red[wid] = s;
    __syncthreads();
    if (threadIdx.x == 0) partial[b * 16 + i] = red[0] + red[1] + red[2] + red[3];
}

__global__ __launch_bounds__(256) void init_kernel(const float* __restrict__ x,
                                                   const float* __restrict__ partial,
                                                   float* __restrict__ norms,
                                                   ushort* __restrict__ Yenc,
                                                   ushort* __restrict__ Tenc) {
    int b = blockIdx.y;
    float s = 0.f;
    #pragma unroll
    for (int p = 0; p < 16; ++p) s += partial[b * 16 + p];
    float nrm = sqrtf(s);
    if (blockIdx.x == 0 && threadIdx.x == 0) norms[b] = nrm;
    float inv = 1.0f / nrm;
    int idx = (blockIdx.x * 256 + threadIdx.x) * 4;
    int r = idx >> 9;
    int c = idx & 511;
    float4 v = *(const float4*)(x + (size_t)b * DIM * DIM + idx);
    float yv[4] = {v.x * inv, v.y * inv, v.z * inv, v.w * inv};
    size_t base = (size_t)b * DIM * KENC + (size_t)r * KENC;
    ushort yhi[4], ylo[4], thi[4], tlo[4];
    #pragma unroll
    for (int j = 0; j < 4; ++j) {
        float y = yv[j];
        yhi[j] = f2bf(y);
        ylo[j] = f2bf(y - bf2f(yhi[j]));
        float t = ((c + j) == r ? 1.5f : 0.0f) - 0.5f * y;
        thi[j] = f2bf(t);
        tlo[j] = f2bf(t - bf2f(thi[j]));
    }
    *(ushort4*)(Yenc + base + c)       = *(ushort4*)yhi;
    *(ushort4*)(Yenc + base + 512 + c) = *(ushort4*)ylo;
    *(ushort4*)(Tenc + base + c)       = *(ushort4*)thi;
    *(ushort4*)(Tenc + base + 512 + c) = *(ushort4*)tlo;
}

// Quarter-unit staging: each call issues 2 global_load_lds (one plane, both halves
// of the 512-slot chunk space). plane layout: 256 rows * 32 elem; physical chunk
// pc of row r holds logical chunk pc ^ ((r>>1)&3). LDS dest = base + vt*16B.
// FIFO ledger counts 2 per call; hi unit = {Ahi,Bhi} = 4, lo unit = {Alo,Blo} = 4.
__device__ __forceinline__ void stage_plane(ushort* dst, const ushort* src, int k0, int tid) {
    #pragma unroll
    for (int s = 0; s < 2; ++s) {
        int vt = tid + s * 512;
        int row = vt >> 2;
        int pc  = vt & 3;
        int kc  = ((pc ^ ((row >> 1) & 3)) << 3);
        gload16(src + (size_t)row * KENC + k0 + kc, &dst[vt * 8]);
    }
}

__device__ __forceinline__ void store_enc(ushort* Cenc, size_t matoff, int gr, int gc, float v) {
    ushort hi = f2bf(v);
    ushort lo = f2bf(v - bf2f(hi));
    Cenc[matoff + (size_t)gr * KENC + gc] = hi;
    Cenc[matoff + (size_t)gr * KENC + 512 + gc] = lo;
}

// 256x256 tile, 512 threads (8 waves, each a 128x64 sub-tile), double-buffered LDS.
// m201-faithful FINE-PHASE schedule: 6 phases per K-tile, each a 16-MFMA cluster:
//   {ds_reads for THIS phase's MFMA || stage one plane of next tile} -> BAR ->
//   setprio(1) MFMA x16 setprio(0) -> BAR
// Phase map (products hh, hl, lh of the bf16-split encoding):
//   P1: read ah03,bh  + stage Ahi'   | MFMA ah03 x bh
//   P2: read ah47     + stage Bhi'   | MFMA ah47 x bh | WAITVM(4) publish lo(kt)
//   P3: read bl       + stage Alo'   | MFMA ah03 x bl
//   P4:                 stage Blo'   | MFMA ah47 x bl
//   P5: read al03                    | MFMA al03 x bh
//   P6: read al47                    | MFMA al47 x bh | WAITVM(4) publish hi(kt+1)
// vmcnt ledger (2 loads/plane, FIFO): tile-entry invariant = {lo(kt)} = 4 out.
//   P2 wait: out = lo4+Ahi'2+Bhi'2 = 8 -> 4 proves lo(kt) (oldest).
//   P6 wait: out = hi'4+Alo'2+Blo'2 = 8 -> 4 proves hi(kt+1). Tail: vmcnt(0) @P2.
// Publish discipline: every WAITVM sits before a trailing BARRIER; cross-wave LDS
// reads of DMA'd data happen only after that barrier (vmcnt is per-wave).
// Reads feed same-phase MFMA -> no cross-phase operand liveness -> ~80 frag VGPRs,
// no spill (round-4 lesson). Barrier rate = 12/96 MFMA = m201's 8/64.
// MODE 0: T-enc = 1.5I - 0.5*C   MODE 1: C-enc   MODE 2: fp32 C*sqrt(normA)
template <int MODE>
__global__ __launch_bounds__(512, 2) void gemm_bt(const ushort* __restrict__ A,
                                                  const ushort* __restrict__ B,
                                                  ushort* __restrict__ Cenc,
                                                  float* __restrict__ Cout,
                                                  const float* __restrict__ norms) {
    __shared__ __attribute__((aligned(16))) ushort sm[2 * BUFE];  // 128 KB

    int f = blockIdx.x;           // 256 blocks: 64 matrices x 4 quadrant-tiles
    int xcd = f & 7;
    int g   = f >> 3;             // 0..31
    int b   = xcd + 8 * (g >> 2); // 8 matrices per XCD (4 co-tiles each)
    int t   = g & 3;
    int bm  = t >> 1;
    int bn  = t & 1;

    size_t matoff = (size_t)b * DIM * KENC;
    const ushort* Ag = A + matoff + (size_t)bm * BM * KENC;
    const ushort* Bg = B + matoff + (size_t)bn * BN * KENC;

    int tid = threadIdx.x;
    int wave = tid >> 6, lane = tid & 63;
    int lane15 = lane & 15, quad = lane >> 4;
    int wrow = (wave >> 2) * 128;   // 2 row-groups of 128
    int wcol = (wave & 3) * 64;     // 4 col-groups of 64
    int s2 = (lane15 >> 1) & 3;
    int fo = ((quad ^ s2) << 3);

    floatx4 acc[8][4];
    #pragma unroll
    for (int i = 0; i < 8; ++i)
        #pragma unroll
        for (int j = 0; j < 4; ++j)
            acc[i][j] = (floatx4){0.f, 0.f, 0.f, 0.f};

    // prologue: stage tile 0 (Ahi,Bhi,Alo,Blo = 8 loads); publish hi(0) (4 left)
    stage_plane(sm,         Ag,       0, tid);   // Ahi
    stage_plane(sm + 16384, Bg,       0, tid);   // Bhi
    stage_plane(sm + 8192,  Ag + 512, 0, tid);   // Alo
    stage_plane(sm + 24576, Bg + 512, 0, tid);   // Blo
    WAITVM(4);
    BARRIER();

    for (int kt = 0; kt < NKT; ++kt) {
        const ushort* cur = sm + (kt & 1) * BUFE;
        ushort* nxt = sm + ((kt + 1) & 1) * BUFE;
        const ushort* Ash = cur;
        const ushort* Asl = cur + 8192;
        const ushort* Bsh = cur + 16384;
        const ushort* Bsl = cur + 24576;
        int k1 = (kt + 1) * BKT;
        bool pre = (kt + 1 < NKT);

        short8 ah03[4], ah47[4], bh[4], bl[4], al[4];

        // ---- P1: read ah03 + bh; stage Ahi(kt+1); MFMA ah03 x bh ----
        #pragma unroll
        for (int i = 0; i < 4; ++i)
            ah03[i] = *(const short8*)&Ash[(wrow + i * 16 + lane15) * BKT + fo];
        #pragma unroll
        for (int j = 0; j < 4; ++j)
            bh[j] = *(const short8*)&Bsh[(wcol + j * 16 + lane15) * BKT + fo];
        if (pre) stage_plane(nxt, Ag, k1, tid);
        BARRIER();
        __builtin_amdgcn_s_setprio(1);
        #pragma unroll
        for (int i = 0; i < 4; ++i)
            #pragma unroll
            for (int j = 0; j < 4; ++j)
                acc[i][j] = __builtin_amdgcn_mfma_f32_16x16x32_bf16(ah03[i], bh[j], acc[i][j], 0, 0, 0);
        __builtin_amdgcn_s_setprio(0);
        BARRIER();

        // ---- P2: read ah47; stage Bhi(kt+1); MFMA ah47 x bh; publish lo(kt) ----
        #pragma unroll
        for (int i = 0; i < 4; ++i)
            ah47[i] = *(const short8*)&Ash[(wrow + (i + 4) * 16 + lane15) * BKT + fo];
        if (pre) stage_plane(nxt + 16384, Bg, k1, tid);
        BARRIER();
        __builtin_amdgcn_s_setprio(1);
        #pragma unroll
        for (int i = 0; i < 4; ++i)
            #pragma unroll
            for (int j = 0; j < 4; ++j)
                acc[i + 4][j] = __builtin_amdgcn_mfma_f32_16x16x32_bf16(ah47[i], bh[j], acc[i + 4][j], 0, 0, 0);
        __builtin_amdgcn_s_setprio(0);
        if (pre) { WAITVM(4); } else { WAITVM(0); }
        BARRIER();

        // ---- P3: read bl; stage Alo(kt+1); MFMA ah03 x bl ----
        #pragma unroll
        for (int j = 0; j < 4; ++j)
            bl[j] = *(const short8*)&Bsl[(wcol + j * 16 + lane15) * BKT + fo];
        if (pre) stage_plane(nxt + 8192, Ag + 512, k1, tid);
        BARRIER();
        __builtin_amdgcn_s_setprio(1);
        #pragma unroll
        for (int i = 0; i < 4; ++i)
            #pragma unroll
            for (int j = 0; j < 4; ++j)
                acc[i][j] = __builtin_amdgcn_mfma_f32_16x16x32_bf16(ah03[i], bl[j], acc[i][j], 0, 0, 0);
        __builtin_amdgcn_s_setprio(0);
        BARRIER();

        // ---- P4: stage Blo(kt+1); MFMA ah47 x bl ----
        if (pre) stage_plane(nxt + 24576, Bg + 512, k1, tid);
        BARRIER();
        __builtin_amdgcn_s_setprio(1);
        #pragma unroll
        for (int i = 0; i < 4; ++i)
            #pragma unroll
            for (int j = 0; j < 4; ++j)
                acc[i + 4][j] = __builtin_amdgcn_mfma_f32_16x16x32_bf16(ah47[i], bl[j], acc[i + 4][j], 0, 0, 0);
        __builtin_amdgcn_s_setprio(0);
        BARRIER();

        // ---- P5: read al03; MFMA al03 x bh ----
        #pragma unroll
        for (int i = 0; i < 4; ++i)
            al[i] = *(const short8*)&Asl[(wrow + i * 16 + lane15) * BKT + fo];
        BARRIER();
        __builtin_amdgcn_s_setprio(1);
        #pragma unroll
        for (int i = 0; i < 4; ++i)
            #pragma unroll
            for (int j = 0; j < 4; ++j)
                acc[i][j] = __builtin_amdgcn_mfma_f32_16x16x32_bf16(al[i], bh[j], acc[i][j], 0, 0, 0);
        __builtin_amdgcn_s_setprio(0);
        BARRIER();

        // ---- P6: read al47; MFMA al47 x bh; publish hi(kt+1) ----
        #pragma unroll
        for (int i = 0; i < 4; ++i)
            al[i] = *(const short8*)&Asl[(wrow + (i + 4) * 16 + lane15) * BKT + fo];
        BARRIER();
        __builtin_amdgcn_s_setprio(1);
        #pragma unroll
        for (int i = 0; i < 4; ++i)
            #pragma unroll
            for (int j = 0; j < 4; ++j)
                acc[i + 4][j] = __builtin_amdgcn_mfma_f32_16x16x32_bf16(al[i], bh[j], acc[i + 4][j], 0, 0, 0);
        __builtin_amdgcn_s_setprio(0);
        if (pre) WAITVM(4);
        BARRIER();
    }

    float scale = (MODE == 2) ? sqrtf(norms[b]) : 0.f;
    #pragma unroll
    for (int i = 0; i < 8; ++i) {
        int gr0 = bm * BM + wrow + i * 16 + quad * 4;
        #pragma unroll
        for (int j = 0; j < 4; ++j) {
            int gc = bn * BN + wcol + j * 16 + lane15;
            #pragma unroll
            for (int rr = 0; rr < 4; ++rr) {
                int gr = gr0 + rr;
                float cv = acc[i][j][rr];
                if (MODE == 0) {
                    store_enc(Cenc, matoff, gr, gc, (gr == gc ? 1.5f : 0.0f) - 0.5f * cv);
                } else if (MODE == 1) {
                    store_enc(Cenc, matoff, gr, gc, cv);
                } else {
                    Cout[(size_t)b * DIM * DIM + (size_t)gr * DIM + gc] = cv * scale;
                }
            }
        }
    }
}

extern "C" void kernel_launch(void* const* d_in, const int* in_sizes, int n_in,
                              void* d_out, int out_size, void* d_ws, size_t ws_size,
                              hipStream_t stream) {
    const float* x = (const float*)d_in[0];  // d_in[1] = I, unused
    float* out = (float*)d_out;

    const size_t MATB = (size_t)BATCH * DIM * KENC * sizeof(ushort);  // 64 MB
    char* ws = (char*)d_ws;
    ushort* W0 = (ushort*)(ws + 0 * MATB);
    ushort* W1 = (ushort*)(ws + 1 * MATB);
    ushort* W2 = (ushort*)(ws + 2 * MATB);
    float* partial = (float*)(ws + 3 * MATB);          // 192 MB + 4 KB total
    float* norms   = (float*)(ws + 3 * MATB + 4096);
    ushort* D = (ushort*)d_out;  // encoded scratch slot #4; final fp32 GEMM overwrites last

    dim3 gblk(512);
    dim3 g1(256);

    norm_partial_kernel<<<dim3(16, BATCH), 256, 0, stream>>>(x, partial);
    init_kernel<<<dim3(256, BATCH), 256, 0, stream>>>(x, partial, norms, W0, W1);  // Y0->W0, T1(=Z1)->W1

    // iter 1: Y1 = Y0*T1 -> W2 ; Z1 = T1 (W1).             live: Y1=W2, Z1=W1   free: W0, D
    gemm_bt<1><<<g1, gblk, 0, stream>>>(W0, W1, W2, nullptr, nullptr);
    // iter 2: T2 = f(Z1*Y1) -> W0                          live: Y1=W2, Z1=W1, T2=W0   free: D
    gemm_bt<0><<<g1, gblk, 0, stream>>>(W1, W2, W0, nullptr, nullptr);
    gemm_bt<1><<<g1, gblk, 0, stream>>>(W2, W0, D, nullptr, nullptr);   // Y2 -> D
    gemm_bt<1><<<g1, gblk, 0, stream>>>(W0, W1, W2, nullptr, nullptr);  // Z2 = T2*Z1 -> W2
    // iter 3
    gemm_bt<0><<<g1, gblk, 0, stream>>>(W2, D, W0, nullptr, nullptr);   // T3 -> W0
    gemm_bt<1><<<g1, gblk, 0, stream>>>(D, W0, W1, nullptr, nullptr);   // Y3 -> W1
    gemm_bt<1><<<g1, gblk, 0, stream>>>(W0, W2, D, nullptr, nullptr);   // Z3 = T3*Z2 -> D
    // iter 4
    gemm_bt<0><<<g1, gblk, 0, stream>>>(D, W1, W0, nullptr, nullptr);   // T4 -> W0
    gemm_bt<1><<<g1, gblk, 0, stream>>>(W1, W0, W2, nullptr, nullptr);  // Y4 -> W2
    gemm_bt<1><<<g1, gblk, 0, stream>>>(W0, D, W1, nullptr, nullptr);   // Z4 = T4*Z3 -> W1
    // iter 5
    gemm_bt<0><<<g1, gblk, 0, stream>>>(W1, W2, W0, nullptr, nullptr);  // T5 -> W0
    gemm_bt<2><<<g1, gblk, 0, stream>>>(W2, W0, nullptr, out, norms);   // out = Y4*T5*sqrt(n)
}